// Round 2
// baseline (19.679 us; speedup 1.0000x reference)
//
#include <hip/hip_runtime.h>
#include <math.h>

// AUROC pairwise-hinge surrogate, N = 16384.
//
// Algebraic collapse (round 0, verified absmax = 0.0):
//   s = sigmoid(y_pred) in (0,1) => 1 - (s_p - s_n) in (0,2) => hinge never
//   clips => total = P*Q - Q*Sp + P*Sn => loss = 1 - Sp/P + Sn/Q.
//
// Round 1 change: the single 1024-thread block put the whole 128 KB fetch on
// ONE CU (~5.5 us at ~10 B/cyc/CU HBM path). Now 16 blocks x 256 threads
// (one float4+int4 per thread) spread the fetch over 16 CUs. Cross-block
// combine is DETERMINISTIC: block partials go to u64 fixed-point (2^36 scale)
// via integer atomicAdd (associative, order-independent); the last block
// (atomic counter) finishes. ws accumulators are zeroed by a tiny init kernel
// every call (ws is poisoned once and never re-poisoned -> no cross-call state).

#define TPB   256
#define NBLK  16              // 16384 / 4 / 256
#define SCALE 68719476736.0   // 2^36

// acc layout (u64): [0]=cp [1]=cq [2]=sp_fix [3]=sn_fix [4]=counter
__global__ void auroc_init(unsigned long long* __restrict__ acc) {
    if (threadIdx.x < 8) acc[threadIdx.x] = 0ull;
}

__global__ __launch_bounds__(TPB)
void auroc_main(const float* __restrict__ yp,
                const int*   __restrict__ yt,
                float*       __restrict__ out,
                unsigned long long* __restrict__ acc,
                int n)
{
    const int tid = threadIdx.x;
    const int n4  = n >> 2;

    float sp = 0.0f, sn = 0.0f;
    int   cp = 0,    cq = 0;

    // Grid-stride over float4 quads (exactly one iteration at N=16384).
    for (int i = blockIdx.x * TPB + tid; i < n4; i += gridDim.x * TPB) {
        float4 x = ((const float4*)yp)[i];
        int4   t = ((const int4*)yt)[i];
        float s;
        s = 1.0f / (1.0f + __expf(-x.x)); if (t.x == 1) { sp += s; ++cp; } else if (t.x == 0) { sn += s; ++cq; }
        s = 1.0f / (1.0f + __expf(-x.y)); if (t.y == 1) { sp += s; ++cp; } else if (t.y == 0) { sn += s; ++cq; }
        s = 1.0f / (1.0f + __expf(-x.z)); if (t.z == 1) { sp += s; ++cp; } else if (t.z == 0) { sn += s; ++cq; }
        s = 1.0f / (1.0f + __expf(-x.w)); if (t.w == 1) { sp += s; ++cp; } else if (t.w == 0) { sn += s; ++cq; }
    }
    // Scalar tail (no-op for N = 16384).
    if (blockIdx.x == 0) {
        for (int i = (n4 << 2) + tid; i < n; i += TPB) {
            float s = 1.0f / (1.0f + __expf(-yp[i]));
            int t = yt[i];
            if (t == 1) { sp += s; ++cp; } else if (t == 0) { sn += s; ++cq; }
        }
    }

    float fp = (float)cp, fq = (float)cq;

    // Wave-64 butterfly.
    #pragma unroll
    for (int off = 32; off > 0; off >>= 1) {
        sp += __shfl_down(sp, off);
        sn += __shfl_down(sn, off);
        fp += __shfl_down(fp, off);
        fq += __shfl_down(fq, off);
    }

    // Cross-wave (4 waves) via LDS.
    __shared__ float red[4][4];
    const int wave = tid >> 6, lane = tid & 63;
    if (lane == 0) { red[wave][0]=sp; red[wave][1]=sn; red[wave][2]=fp; red[wave][3]=fq; }
    __syncthreads();

    if (tid == 0) {
        float bsp=0, bsn=0, bfp=0, bfq=0;
        #pragma unroll
        for (int w = 0; w < 4; ++w) { bsp+=red[w][0]; bsn+=red[w][1]; bfp+=red[w][2]; bfq+=red[w][3]; }

        // Deterministic cross-block combine: integer atomics only.
        atomicAdd(&acc[0], (unsigned long long)(bfp + 0.5f));
        atomicAdd(&acc[1], (unsigned long long)(bfq + 0.5f));
        atomicAdd(&acc[2], (unsigned long long)((double)bsp * SCALE));
        atomicAdd(&acc[3], (unsigned long long)((double)bsn * SCALE));
        __threadfence();
        unsigned long long old = atomicAdd(&acc[4], 1ull);
        if (old == (unsigned long long)(gridDim.x - 1)) {
            // Last block: device-coherent reads via atomic RMW of 0.
            unsigned long long P_  = atomicAdd(&acc[0], 0ull);
            unsigned long long Q_  = atomicAdd(&acc[1], 0ull);
            unsigned long long SpF = atomicAdd(&acc[2], 0ull);
            unsigned long long SnF = atomicAdd(&acc[3], 0ull);
            double P = (double)P_, Q = (double)Q_;
            double Sp = (double)SpF * (1.0 / SCALE);
            double Sn = (double)SnF * (1.0 / SCALE);
            double res = (P > 0.0 && Q > 0.0) ? (1.0 - Sp / P + Sn / Q) : 0.0;
            out[0] = (float)res;
        }
    }
}

extern "C" void kernel_launch(void* const* d_in, const int* in_sizes, int n_in,
                              void* d_out, int out_size, void* d_ws, size_t ws_size,
                              hipStream_t stream) {
    const float* y_pred = (const float*)d_in[0];
    const int*   y_true = (const int*)d_in[1];
    float* out = (float*)d_out;
    unsigned long long* acc = (unsigned long long*)d_ws;
    const int n = in_sizes[0];   // 16384

    auroc_init<<<1, 64, 0, stream>>>(acc);
    auroc_main<<<NBLK, TPB, 0, stream>>>(y_pred, y_true, out, acc, n);
}

// Round 3
// 9.718 us; speedup vs baseline: 2.0251x; 2.0251x over previous
//
#include <hip/hip_runtime.h>
#include <math.h>

// AUROC pairwise-hinge surrogate loss, N = 16384.
//
// Algebraic collapse (verified absmax = 0.0 in round 1):
//   s = sigmoid(y_pred) in (0,1)  =>  s_p - s_n in (-1,1)
//   =>  1 - (s_p - s_n) in (0,2)  =>  relu(1 - diff) == 1 - diff for EVERY
//   (pos, neg) pair.  Hence
//     total = P*Q - Q*Sp + P*Sn   =>   loss = 1 - Sp/P + Sn/Q
//   with Sp/Sn = sum of sigmoid over positives/negatives.
//   The O(N^2) pairwise sum collapses to one O(N) reduction.
//
// Round-2 post-mortem: marginal graph-node cost ~10 us (1 node = 9.67 us,
// 2 nodes = 19.68 us). Exec time of this single-block kernel is ~0.2-0.4 us
// (inputs L2-warm across replays). => launch-overhead-bound; one kernel node,
// single block is the floor. Multi-block schemes need either a second init
// node (+10 us) or cooperative launch (no gain over ~0.3 us exec).

__global__ __launch_bounds__(1024)
void auroc_reduce(const float* __restrict__ yp,
                  const int*   __restrict__ yt,
                  float*       __restrict__ out,
                  int n)
{
    const int tid = threadIdx.x;

    float sp = 0.0f, sn = 0.0f;   // sum of sigmoid over pos / neg
    int   cp = 0,    cq = 0;      // counts of pos / neg

    // Vectorized main loop: float4 / int4, lane-contiguous (coalesced).
    const int n4 = n >> 2;
    const float4* __restrict__ yp4 = (const float4*)yp;
    const int4*   __restrict__ yt4 = (const int4*)yt;
    for (int i = tid; i < n4; i += 1024) {
        float4 x = yp4[i];
        int4   t = yt4[i];
        float s;
        s = 1.0f / (1.0f + __expf(-x.x)); if (t.x == 1) { sp += s; ++cp; } else if (t.x == 0) { sn += s; ++cq; }
        s = 1.0f / (1.0f + __expf(-x.y)); if (t.y == 1) { sp += s; ++cp; } else if (t.y == 0) { sn += s; ++cq; }
        s = 1.0f / (1.0f + __expf(-x.z)); if (t.z == 1) { sp += s; ++cp; } else if (t.z == 0) { sn += s; ++cq; }
        s = 1.0f / (1.0f + __expf(-x.w)); if (t.w == 1) { sp += s; ++cp; } else if (t.w == 0) { sn += s; ++cq; }
    }
    // Scalar tail (n % 4 != 0 safety; no-op for N = 16384).
    for (int i = (n4 << 2) + tid; i < n; i += 1024) {
        float s = 1.0f / (1.0f + __expf(-yp[i]));
        int t = yt[i];
        if (t == 1) { sp += s; ++cp; } else if (t == 0) { sn += s; ++cq; }
    }

    float fp = (float)cp, fq = (float)cq;

    // Wave-level butterfly reduction (wave = 64 lanes on CDNA).
    #pragma unroll
    for (int off = 32; off > 0; off >>= 1) {
        sp += __shfl_down(sp, off);
        sn += __shfl_down(sn, off);
        fp += __shfl_down(fp, off);
        fq += __shfl_down(fq, off);
    }

    // Cross-wave reduction through LDS (16 waves in a 1024-thread block).
    __shared__ float red[16][4];
    const int wave = tid >> 6;
    const int lane = tid & 63;
    if (lane == 0) {
        red[wave][0] = sp;
        red[wave][1] = sn;
        red[wave][2] = fp;
        red[wave][3] = fq;
    }
    __syncthreads();

    if (tid == 0) {
        float tsp = 0.0f, tsn = 0.0f, tp = 0.0f, tq = 0.0f;
        #pragma unroll
        for (int w = 0; w < 16; ++w) {
            tsp += red[w][0];
            tsn += red[w][1];
            tp  += red[w][2];
            tq  += red[w][3];
        }
        float denom = tp * tq;
        float total = tp * tq - tq * tsp + tp * tsn;
        out[0] = (denom > 0.0f) ? (total / fmaxf(denom, 1.0f)) : 0.0f;
    }
}

extern "C" void kernel_launch(void* const* d_in, const int* in_sizes, int n_in,
                              void* d_out, int out_size, void* d_ws, size_t ws_size,
                              hipStream_t stream) {
    const float* y_pred = (const float*)d_in[0];
    const int*   y_true = (const int*)d_in[1];
    float* out = (float*)d_out;
    const int n = in_sizes[0];   // 16384

    auroc_reduce<<<1, 1024, 0, stream>>>(y_pred, y_true, out, n);
}